// Round 1
// baseline (78.908 us; speedup 1.0000x reference)
//
#include <hip/hip_runtime.h>
#include <math.h>

// Problem constants (reference: N, M, D_IN = 2048, 2048, 16)
constexpr int N_ROWS = 2048;
constexpr int M_COLS = 2048;
constexpr int D = 16;

constexpr int BM = 256;  // columns per block (= blockDim.x), coalesced stores
constexpr int BN = 32;   // rows per block tile (staged in LDS)

// out[n,m] = var * exp(-0.5*sq) * ( S + (D-1-sq)*wsum )
//   diff_d = (X[n,d]-X2[m,d])/ls_d ; sq = sum diff^2 ; S = sum diff^2 * w_d
//   w_d = 1/ls_d^2 ; wsum = sum w_d ; ls = softplus(uls), var = softplus(uv)
__global__ __launch_bounds__(256, 4) void dfk_kernel(
    const float* __restrict__ X, const float* __restrict__ X2,
    const float* __restrict__ uls, const float* __restrict__ uv,
    float* __restrict__ out) {
  __shared__ float shX[BN * D];  // scaled X rows, 32*16*4 = 2 KB

  const int tid = threadIdx.x;
  const int m = blockIdx.x * BM + tid;
  const int n0 = blockIdx.y * BN;

  // --- softplus params (redundant per thread; tiny) ---
  float inv_ls[D], w[D];
  float wsum = 0.f;
#pragma unroll
  for (int d = 0; d < D; ++d) {
    float u = uls[d];
    // numerically-stable softplus: max(u,0) + log1p(exp(-|u|))
    float ls = fmaxf(u, 0.f) + log1pf(__expf(-fabsf(u)));
    float il = 1.f / ls;
    inv_ls[d] = il;
    float wd = il * il;
    w[d] = wd;
    wsum += wd;
  }
  const float u0 = uv[0];
  const float var = fmaxf(u0, 0.f) + log1pf(__expf(-fabsf(u0)));

  // --- stage BN rows of X/ls into LDS: BN*D = 512 floats = 128 float4 ---
  if (tid < (BN * D) / 4) {
    const int r = tid >> 2;   // row 0..31
    const int c4 = tid & 3;   // quad 0..3
    float4 v = ((const float4*)(X + (size_t)(n0 + r) * D))[c4];
    v.x *= inv_ls[c4 * 4 + 0];
    v.y *= inv_ls[c4 * 4 + 1];
    v.z *= inv_ls[c4 * 4 + 2];
    v.w *= inv_ls[c4 * 4 + 3];
    ((float4*)shX)[tid] = v;
  }

  // --- this thread's X2 row, scaled, in registers ---
  float x2[D];
#pragma unroll
  for (int q = 0; q < 4; ++q) {
    float4 v = ((const float4*)(X2 + (size_t)m * D))[q];
    x2[q * 4 + 0] = v.x * inv_ls[q * 4 + 0];
    x2[q * 4 + 1] = v.y * inv_ls[q * 4 + 1];
    x2[q * 4 + 2] = v.z * inv_ls[q * 4 + 2];
    x2[q * 4 + 3] = v.w * inv_ls[q * 4 + 3];
  }
  __syncthreads();

  const float c3 = (float)D - 1.0f;
#pragma unroll 4
  for (int i = 0; i < BN; ++i) {
    // broadcast LDS reads (all lanes same address -> conflict-free)
    float xl[D];
#pragma unroll
    for (int q = 0; q < 4; ++q) {
      float4 v = ((const float4*)(shX + i * D))[q];
      xl[q * 4 + 0] = v.x;
      xl[q * 4 + 1] = v.y;
      xl[q * 4 + 2] = v.z;
      xl[q * 4 + 3] = v.w;
    }
    float sq = 0.f, s = 0.f;
#pragma unroll
    for (int d = 0; d < D; ++d) {
      const float diff = xl[d] - x2[d];
      const float d2 = diff * diff;
      sq += d2;
      s = fmaf(d2, w[d], s);
    }
    const float k2 = __expf(-0.5f * sq);
    const float res = var * k2 * fmaf(c3 - sq, wsum, s);
    out[(size_t)(n0 + i) * M_COLS + m] = res;
  }
}

extern "C" void kernel_launch(void* const* d_in, const int* in_sizes, int n_in,
                              void* d_out, int out_size, void* d_ws, size_t ws_size,
                              hipStream_t stream) {
  const float* X = (const float*)d_in[0];    // (2048, 16)
  const float* X2 = (const float*)d_in[1];   // (2048, 16)
  const float* uls = (const float*)d_in[2];  // (16,)
  const float* uv = (const float*)d_in[3];   // (1,)
  float* out = (float*)d_out;                // (2048, 2048) fp32

  dim3 grid(M_COLS / BM, N_ROWS / BN);  // (8, 64) = 512 blocks
  dfk_kernel<<<grid, dim3(BM), 0, stream>>>(X, X2, uls, uv, out);
}

// Round 2
// 77.752 us; speedup vs baseline: 1.0149x; 1.0149x over previous
//
#include <hip/hip_runtime.h>
#include <math.h>

// Problem constants (reference: N, M, D_IN = 2048, 2048, 16)
constexpr int N_ROWS = 2048;
constexpr int M_COLS = 2048;
constexpr int D = 16;

constexpr int BM = 256;  // columns per block (= blockDim.x), coalesced stores
constexpr int BN = 32;   // rows per block tile (staged in LDS)

// out[n,m] = var * exp(-0.5*sq) * ( S + (D-1-sq)*wsum )
// dot form:
//   sq = Xs[n] + X2s[m] - 2*dot(xl[n], x2l[m])
//   S  = Xw[n] + X2w[m] - 2*dot(xl[n], x2lw[m]),  x2lw_d = x2l_d * w_d
//   w_d = 1/ls_d^2 ; wsum = sum w_d ; ls = softplus(uls), var = softplus(uv)
__global__ __launch_bounds__(256, 4) void dfk_kernel(
    const float* __restrict__ X, const float* __restrict__ X2,
    const float* __restrict__ uls, const float* __restrict__ uv,
    float* __restrict__ out) {
  __shared__ float shX[BN * D];   // scaled X rows (2 KB)
  __shared__ float shS[BN * 2];   // per-row (Xs, Xw)

  const int tid = threadIdx.x;
  const int m = blockIdx.x * BM + tid;
  const int n0 = blockIdx.y * BN;

  // --- softplus params (redundant per thread; tiny, runs once) ---
  float inv_ls[D], w[D];
  float wsum = 0.f;
#pragma unroll
  for (int d = 0; d < D; ++d) {
    float u = uls[d];
    float ls = fmaxf(u, 0.f) + log1pf(__expf(-fabsf(u)));  // stable softplus
    float il = 1.f / ls;
    inv_ls[d] = il;
    float wd = il * il;
    w[d] = wd;
    wsum += wd;
  }
  const float u0 = uv[0];
  const float var = fmaxf(u0, 0.f) + log1pf(__expf(-fabsf(u0)));

  // --- stage BN rows of X/ls into LDS + per-row sums (one row per thread) ---
  if (tid < BN) {
    const float* xr = X + (size_t)(n0 + tid) * D;
    float xs = 0.f, xw = 0.f;
#pragma unroll
    for (int q = 0; q < 4; ++q) {
      float4 v = ((const float4*)xr)[q];
      v.x *= inv_ls[q * 4 + 0];
      v.y *= inv_ls[q * 4 + 1];
      v.z *= inv_ls[q * 4 + 2];
      v.w *= inv_ls[q * 4 + 3];
      xs += v.x * v.x + v.y * v.y + v.z * v.z + v.w * v.w;
      xw += v.x * v.x * w[q * 4 + 0] + v.y * v.y * w[q * 4 + 1] +
            v.z * v.z * w[q * 4 + 2] + v.w * v.w * w[q * 4 + 3];
      ((float4*)(shX + tid * D))[q] = v;
    }
    shS[tid * 2 + 0] = xs;
    shS[tid * 2 + 1] = xw;
  }

  // --- this thread's X2 row: scaled (x2l) and weight-scaled (x2lw) ---
  float x2l[D], x2lw[D];
  float X2s = 0.f, X2w = 0.f;
#pragma unroll
  for (int q = 0; q < 4; ++q) {
    float4 v = ((const float4*)(X2 + (size_t)m * D))[q];
#pragma unroll
    for (int j = 0; j < 4; ++j) {
      const int d = q * 4 + j;
      const float e = (&v.x)[j] * inv_ls[d];
      x2l[d] = e;
      x2lw[d] = e * w[d];
      X2s += e * e;
      X2w += e * e * w[d];
    }
  }
  __syncthreads();

  const float c3 = (float)D - 1.0f;
#pragma unroll 2
  for (int i = 0; i < BN; ++i) {
    const float4* row = (const float4*)(shX + i * D);  // broadcast reads
    float dot = 0.f, dotw = 0.f;
#pragma unroll
    for (int q = 0; q < 4; ++q) {
      float4 v = row[q];
      dot = fmaf(v.x, x2l[q * 4 + 0], dot);
      dot = fmaf(v.y, x2l[q * 4 + 1], dot);
      dot = fmaf(v.z, x2l[q * 4 + 2], dot);
      dot = fmaf(v.w, x2l[q * 4 + 3], dot);
      dotw = fmaf(v.x, x2lw[q * 4 + 0], dotw);
      dotw = fmaf(v.y, x2lw[q * 4 + 1], dotw);
      dotw = fmaf(v.z, x2lw[q * 4 + 2], dotw);
      dotw = fmaf(v.w, x2lw[q * 4 + 3], dotw);
    }
    const float sq = shS[i * 2 + 0] + X2s - 2.f * dot;
    const float S = shS[i * 2 + 1] + X2w - 2.f * dotw;
    const float k2 = __expf(-0.5f * sq);
    const float res = var * k2 * fmaf(c3 - sq, wsum, S);
    out[(size_t)(n0 + i) * M_COLS + m] = res;
  }
}

extern "C" void kernel_launch(void* const* d_in, const int* in_sizes, int n_in,
                              void* d_out, int out_size, void* d_ws, size_t ws_size,
                              hipStream_t stream) {
  const float* X = (const float*)d_in[0];    // (2048, 16)
  const float* X2 = (const float*)d_in[1];   // (2048, 16)
  const float* uls = (const float*)d_in[2];  // (16,)
  const float* uv = (const float*)d_in[3];   // (1,)
  float* out = (float*)d_out;                // (2048, 2048) fp32

  dim3 grid(M_COLS / BM, N_ROWS / BN);  // (8, 64) = 512 blocks
  dfk_kernel<<<grid, dim3(BM), 0, stream>>>(X, X2, uls, uv, out);
}

// Round 3
// 70.593 us; speedup vs baseline: 1.1178x; 1.1014x over previous
//
#include <hip/hip_runtime.h>
#include <math.h>

// Problem constants (reference: N, M, D_IN = 2048, 2048, 16)
constexpr int N_ROWS = 2048;
constexpr int M_COLS = 2048;
constexpr int D = 16;

constexpr int BM = 256;  // columns per block (= blockDim.x), coalesced stores
constexpr int BN = 32;   // rows per block tile (staged in LDS)

// out[n,m] = var * exp(-0.5*sq) * ( S + (D-1-sq)*wsum )
// dot form:
//   sq = Xs[n] + X2s[m] - 2*dot(xl[n], x2l[m])
//   S  = Xw[n] + X2w[m] - 2*dot(xl[n], x2lw[m]),  x2lw_d = x2l_d * w_d
//   w_d = 1/ls_d^2 ; wsum = sum w_d ; ls = softplus(uls), var = softplus(uv)
// Softplus computed once per block by 17 threads -> LDS (log1pf/__expf are
// ~30 instr each; doing them 16x per thread was ~25% of kernel time).
__global__ __launch_bounds__(256, 4) void dfk_kernel(
    const float* __restrict__ X, const float* __restrict__ X2,
    const float* __restrict__ uls, const float* __restrict__ uv,
    float* __restrict__ out) {
  __shared__ float sh_par[2 * D + 1];  // inv_ls[16], w[16], var
  __shared__ float shX[BN * D];        // scaled X rows (2 KB)
  __shared__ float shS[BN * 2];        // per-row (Xs, Xw)

  const int tid = threadIdx.x;
  const int m = blockIdx.x * BM + tid;
  const int n0 = blockIdx.y * BN;

  // --- cooperative softplus: lanes 0..15 -> lengthscales, lane 16 -> var ---
  if (tid <= D) {
    const float u = (tid < D) ? uls[tid] : uv[0];
    const float sp = fmaxf(u, 0.f) + log1pf(__expf(-fabsf(u)));  // stable
    if (tid < D) {
      const float il = 1.f / sp;
      sh_par[tid] = il;
      sh_par[D + tid] = il * il;
    } else {
      sh_par[2 * D] = sp;
    }
  }
  __syncthreads();

  float inv_ls[D], w[D];
  float wsum = 0.f;
#pragma unroll
  for (int d = 0; d < D; ++d) {  // broadcast LDS reads, conflict-free
    inv_ls[d] = sh_par[d];
    w[d] = sh_par[D + d];
    wsum += w[d];
  }
  const float var = sh_par[2 * D];

  // --- stage BN rows of X/ls into LDS + per-row sums (one row per thread) ---
  if (tid < BN) {
    const float* xr = X + (size_t)(n0 + tid) * D;
    float xs = 0.f, xw = 0.f;
#pragma unroll
    for (int q = 0; q < 4; ++q) {
      float4 v = ((const float4*)xr)[q];
      v.x *= inv_ls[q * 4 + 0];
      v.y *= inv_ls[q * 4 + 1];
      v.z *= inv_ls[q * 4 + 2];
      v.w *= inv_ls[q * 4 + 3];
      xs += v.x * v.x + v.y * v.y + v.z * v.z + v.w * v.w;
      xw += v.x * v.x * w[q * 4 + 0] + v.y * v.y * w[q * 4 + 1] +
            v.z * v.z * w[q * 4 + 2] + v.w * v.w * w[q * 4 + 3];
      ((float4*)(shX + tid * D))[q] = v;
    }
    shS[tid * 2 + 0] = xs;
    shS[tid * 2 + 1] = xw;
  }

  // --- this thread's X2 row: scaled (x2l) and weight-scaled (x2lw) ---
  float x2l[D], x2lw[D];
  float X2s = 0.f, X2w = 0.f;
#pragma unroll
  for (int q = 0; q < 4; ++q) {
    float4 v = ((const float4*)(X2 + (size_t)m * D))[q];
#pragma unroll
    for (int j = 0; j < 4; ++j) {
      const int d = q * 4 + j;
      const float e = (&v.x)[j] * inv_ls[d];
      x2l[d] = e;
      x2lw[d] = e * w[d];
      X2s += e * e;
      X2w += e * e * w[d];
    }
  }
  __syncthreads();

  const float c3 = (float)D - 1.0f;
#pragma unroll 2
  for (int i = 0; i < BN; ++i) {
    const float4* row = (const float4*)(shX + i * D);  // broadcast reads
    float dot = 0.f, dotw = 0.f;
#pragma unroll
    for (int q = 0; q < 4; ++q) {
      float4 v = row[q];
      dot = fmaf(v.x, x2l[q * 4 + 0], dot);
      dot = fmaf(v.y, x2l[q * 4 + 1], dot);
      dot = fmaf(v.z, x2l[q * 4 + 2], dot);
      dot = fmaf(v.w, x2l[q * 4 + 3], dot);
      dotw = fmaf(v.x, x2lw[q * 4 + 0], dotw);
      dotw = fmaf(v.y, x2lw[q * 4 + 1], dotw);
      dotw = fmaf(v.z, x2lw[q * 4 + 2], dotw);
      dotw = fmaf(v.w, x2lw[q * 4 + 3], dotw);
    }
    const float sq = shS[i * 2 + 0] + X2s - 2.f * dot;
    const float S = shS[i * 2 + 1] + X2w - 2.f * dotw;
    const float k2 = __expf(-0.5f * sq);
    const float res = var * k2 * fmaf(c3 - sq, wsum, S);
    out[(size_t)(n0 + i) * M_COLS + m] = res;
  }
}

extern "C" void kernel_launch(void* const* d_in, const int* in_sizes, int n_in,
                              void* d_out, int out_size, void* d_ws, size_t ws_size,
                              hipStream_t stream) {
  const float* X = (const float*)d_in[0];    // (2048, 16)
  const float* X2 = (const float*)d_in[1];   // (2048, 16)
  const float* uls = (const float*)d_in[2];  // (16,)
  const float* uv = (const float*)d_in[3];   // (1,)
  float* out = (float*)d_out;                // (2048, 2048) fp32

  dim3 grid(M_COLS / BM, N_ROWS / BN);  // (8, 64) = 512 blocks
  dfk_kernel<<<grid, dim3(BM), 0, stream>>>(X, X2, uls, uv, out);
}